// Round 2
// baseline (2084.492 us; speedup 1.0000x reference)
//
#include <hip/hip_runtime.h>
#include <hip/hip_bf16.h>
#include <cstdint>
#include <cstddef>

typedef __bf16 bf16;
typedef __bf16 bf16x8 __attribute__((ext_vector_type(8)));
typedef __bf16 bf16x4v __attribute__((ext_vector_type(4)));
typedef float f32x4 __attribute__((ext_vector_type(4)));

#define NB 2
#define NS 2048
#define NHID 2304
#define NHEADS 8
#define NKVH 4
#define HDIM 256
#define NFF 9216
#define NROWS (NB * NS)      // 4096
#define SCALE_F 0.0625f      // 256^-0.5
#define SOFTCAP_F 50.0f

__device__ __forceinline__ float fast_tanh(float x) {
    x = fminf(fmaxf(x, -10.f), 10.f);
    float e = __expf(2.f * x);
    return (e - 1.f) / (e + 1.f);
}

// ---------------------------------------------------------------------------
// Partial transpose+convert: reads W[k][n] f32 for k in [k0, k0+64*gridK),
// writes bf16 dst[n*dstK + dstOff + (k-k0)].  64x64 tiles.
// Used for the in-place (d_in-resident) weight conversion: pass ranges are
// disjoint from the concurrently-read source bytes by construction.
// ---------------------------------------------------------------------------
__global__ __launch_bounds__(256)
void transpose_cvt_part(const float* __restrict__ W, int N, int k0,
                        bf16* __restrict__ dst, int dstK, int dstOff) {
    __shared__ float tile[64][65];
    const int ntiles = N >> 6;
    const int tk = blockIdx.x / ntiles, tn = blockIdx.x % ntiles;
    const int kk0 = k0 + (tk << 6), n0 = tn << 6;
    const int tr = threadIdx.x >> 4, tc = threadIdx.x & 15;
#pragma unroll
    for (int j = 0; j < 4; ++j) {
        const int r = j * 16 + tr;
        const float4 v = *(const float4*)&W[(size_t)(kk0 + r) * N + n0 + tc * 4];
        tile[r][tc * 4 + 0] = v.x; tile[r][tc * 4 + 1] = v.y;
        tile[r][tc * 4 + 2] = v.z; tile[r][tc * 4 + 3] = v.w;
    }
    __syncthreads();
#pragma unroll
    for (int j = 0; j < 4; ++j) {
        const int n = j * 16 + tr;
        bf16x4v o;
        o.x = (bf16)tile[tc * 4 + 0][n];
        o.y = (bf16)tile[tc * 4 + 1][n];
        o.z = (bf16)tile[tc * 4 + 2][n];
        o.w = (bf16)tile[tc * 4 + 3][n];
        *(bf16x4v*)&dst[(size_t)(n0 + n) * dstK + dstOff + (tk << 6) + tc * 4] = o;
    }
}

// copy temp[n][0..srcK) -> dst[n*dstK + 0..srcK), 16B chunks
__global__ __launch_bounds__(256)
void copy_expand(const bf16* __restrict__ src, bf16* __restrict__ dst,
                 int srcK, int dstK, int total) {
    const int idx = blockIdx.x * 256 + threadIdx.x;
    if (idx >= total) return;
    const int cpr = srcK >> 3;
    const int n = idx / cpr, c = idx % cpr;
    *(uint4*)&dst[(size_t)n * dstK + c * 8] = *(const uint4*)&src[(size_t)n * srcK + c * 8];
}

// ---------------------------------------------------------------------------
// RMSNorm: out = [res +] rmsnorm(src, g).  One block per row, 256 thr, H=2304.
// ---------------------------------------------------------------------------
template <bool ADD, bool OBF>
__global__ __launch_bounds__(256)
void rmsnorm_k(const float* __restrict__ src, const float* __restrict__ res,
               const float* __restrict__ g, void* __restrict__ out) {
    const int row = blockIdx.x;
    const float* xr = src + (size_t)row * NHID;
    float vals[9];
    float ss = 0.f;
#pragma unroll
    for (int j = 0; j < 9; ++j) {
        vals[j] = xr[threadIdx.x + j * 256];
        ss += vals[j] * vals[j];
    }
#pragma unroll
    for (int off = 32; off > 0; off >>= 1) ss += __shfl_xor(ss, off);
    __shared__ float wss[4];
    if ((threadIdx.x & 63) == 0) wss[threadIdx.x >> 6] = ss;
    __syncthreads();
    const float scale = rsqrtf((wss[0] + wss[1] + wss[2] + wss[3]) * (1.f / NHID) + 1e-6f);
#pragma unroll
    for (int j = 0; j < 9; ++j) {
        const int c = threadIdx.x + j * 256;
        float v = vals[j] * scale * (1.f + g[c]);
        if constexpr (ADD) v += res[(size_t)row * NHID + c];
        if constexpr (OBF) ((bf16*)out)[(size_t)row * NHID + c] = (bf16)v;
        else               ((float*)out)[(size_t)row * NHID + c] = v;
    }
}

// ---------------------------------------------------------------------------
// RoPE in-place on bf16 q [4096][2048] and k [4096][1024].
// ---------------------------------------------------------------------------
__global__ __launch_bounds__(256)
void rope_k(bf16* __restrict__ q, bf16* __restrict__ k) {
    const int idx = blockIdx.x * 256 + threadIdx.x;
    const int i = idx & 127;
    const int t = idx >> 7;
    const int head = t % 12;
    const int row = t / 12;
    const int s = row & (NS - 1);
    const float ang = (float)s * exp2f(-(float)i * 0.10381025296523007f);
    float sn, cs;
    sincosf(ang, &sn, &cs);
    bf16* base = (head < 8) ? (q + (size_t)row * 2048 + head * 256 + i)
                            : (k + (size_t)row * 1024 + (head - 8) * 256 + i);
    const float x1 = (float)base[0], x2 = (float)base[128];
    base[0]   = (bf16)(x1 * cs - x2 * sn);
    base[128] = (bf16)(x2 * cs + x1 * sn);
}

// ---------------------------------------------------------------------------
// GEMM: C[M][N] = A[M][K] @ Bt[N][K]^T.  128x128 tile, 4 waves, 4x4 mfma.
// MODE 0: C f32.  MODE 1: C bf16.  MODE 2: C bf16 transposed Vt[b][n][s].
// ---------------------------------------------------------------------------
template <int MODE>
__global__ __launch_bounds__(256)
void gemm_bt(const bf16* __restrict__ A, const bf16* __restrict__ Bt,
             void* __restrict__ C, int M, int N, int K) {
    __shared__ __align__(16) bf16 As[128 * 40];
    __shared__ __align__(16) bf16 Bs[128 * 40];
    const int tid = threadIdx.x;
    const int lane = tid & 63, wave = tid >> 6;
    const int lq = lane & 15, quad = lane >> 4;
    const int ntiles = N >> 7;
    const int tm = blockIdx.x / ntiles, tn = blockIdx.x % ntiles;
    const int m0 = tm << 7, n0 = tn << 7;
    const int wrow = (wave >> 1) << 6, wcol = (wave & 1) << 6;
    f32x4 acc[4][4];
#pragma unroll
    for (int i = 0; i < 4; ++i)
#pragma unroll
        for (int j = 0; j < 4; ++j) acc[i][j] = (f32x4){0.f, 0.f, 0.f, 0.f};

    const int srow = tid >> 2, sc8 = (tid & 3) * 8;
    for (int k0 = 0; k0 < K; k0 += 32) {
        __syncthreads();
#pragma unroll
        for (int j = 0; j < 2; ++j) {
            const int row = j * 64 + srow;
            *(uint4*)&As[row * 40 + sc8] = *(const uint4*)&A[(size_t)(m0 + row) * K + k0 + sc8];
            *(uint4*)&Bs[row * 40 + sc8] = *(const uint4*)&Bt[(size_t)(n0 + row) * K + k0 + sc8];
        }
        __syncthreads();
        bf16x8 af[4], bfr[4];
#pragma unroll
        for (int i = 0; i < 4; ++i) {
            af[i]  = *(const bf16x8*)&As[(wrow + i * 16 + lq) * 40 + quad * 8];
            bfr[i] = *(const bf16x8*)&Bs[(wcol + i * 16 + lq) * 40 + quad * 8];
        }
#pragma unroll
        for (int mi = 0; mi < 4; ++mi)
#pragma unroll
            for (int ni = 0; ni < 4; ++ni)
                acc[mi][ni] = __builtin_amdgcn_mfma_f32_16x16x32_bf16(af[mi], bfr[ni], acc[mi][ni], 0, 0, 0);
    }
#pragma unroll
    for (int mi = 0; mi < 4; ++mi) {
        const int r0 = m0 + wrow + mi * 16 + quad * 4;
#pragma unroll
        for (int ni = 0; ni < 4; ++ni) {
            const int cc = n0 + wcol + ni * 16 + lq;
#pragma unroll
            for (int i = 0; i < 4; ++i) {
                const float v = acc[mi][ni][i];
                if constexpr (MODE == 0) {
                    ((float*)C)[(size_t)(r0 + i) * N + cc] = v;
                } else if constexpr (MODE == 1) {
                    ((bf16*)C)[(size_t)(r0 + i) * N + cc] = (bf16)v;
                } else {
                    const int m = r0 + i, bb = m >> 11, ss = m & 2047;
                    ((bf16*)C)[((size_t)bb * N + cc) * 2048 + ss] = (bf16)v;
                }
            }
        }
    }
}

// ---------------------------------------------------------------------------
// Fused GeGLU GEMM: C[M][N] = gelu_tanh(A@Wg) * (A@Wu), C bf16.
// ---------------------------------------------------------------------------
__global__ __launch_bounds__(256)
void geglu_gemm(const bf16* __restrict__ A, const bf16* __restrict__ Bg,
                const bf16* __restrict__ Bu, bf16* __restrict__ C,
                int M, int N, int K) {
    __shared__ __align__(16) bf16 As[128 * 40];
    __shared__ __align__(16) bf16 Bgs[128 * 40];
    __shared__ __align__(16) bf16 Bus[128 * 40];
    const int tid = threadIdx.x;
    const int lane = tid & 63, wave = tid >> 6;
    const int lq = lane & 15, quad = lane >> 4;
    const int ntiles = N >> 7;
    const int tm = blockIdx.x / ntiles, tn = blockIdx.x % ntiles;
    const int m0 = tm << 7, n0 = tn << 7;
    const int wrow = (wave >> 1) << 6, wcol = (wave & 1) << 6;
    f32x4 accg[4][4], accu[4][4];
#pragma unroll
    for (int i = 0; i < 4; ++i)
#pragma unroll
        for (int j = 0; j < 4; ++j) {
            accg[i][j] = (f32x4){0.f, 0.f, 0.f, 0.f};
            accu[i][j] = (f32x4){0.f, 0.f, 0.f, 0.f};
        }
    const int srow = tid >> 2, sc8 = (tid & 3) * 8;
    for (int k0 = 0; k0 < K; k0 += 32) {
        __syncthreads();
#pragma unroll
        for (int j = 0; j < 2; ++j) {
            const int row = j * 64 + srow;
            *(uint4*)&As[row * 40 + sc8]  = *(const uint4*)&A[(size_t)(m0 + row) * K + k0 + sc8];
            *(uint4*)&Bgs[row * 40 + sc8] = *(const uint4*)&Bg[(size_t)(n0 + row) * K + k0 + sc8];
            *(uint4*)&Bus[row * 40 + sc8] = *(const uint4*)&Bu[(size_t)(n0 + row) * K + k0 + sc8];
        }
        __syncthreads();
        bf16x8 af[4], bg[4], bu[4];
#pragma unroll
        for (int i = 0; i < 4; ++i) {
            af[i] = *(const bf16x8*)&As[(wrow + i * 16 + lq) * 40 + quad * 8];
            bg[i] = *(const bf16x8*)&Bgs[(wcol + i * 16 + lq) * 40 + quad * 8];
            bu[i] = *(const bf16x8*)&Bus[(wcol + i * 16 + lq) * 40 + quad * 8];
        }
#pragma unroll
        for (int mi = 0; mi < 4; ++mi)
#pragma unroll
            for (int ni = 0; ni < 4; ++ni) {
                accg[mi][ni] = __builtin_amdgcn_mfma_f32_16x16x32_bf16(af[mi], bg[ni], accg[mi][ni], 0, 0, 0);
                accu[mi][ni] = __builtin_amdgcn_mfma_f32_16x16x32_bf16(af[mi], bu[ni], accu[mi][ni], 0, 0, 0);
            }
    }
#pragma unroll
    for (int mi = 0; mi < 4; ++mi) {
        const int r0 = m0 + wrow + mi * 16 + quad * 4;
#pragma unroll
        for (int ni = 0; ni < 4; ++ni) {
            const int cc = n0 + wcol + ni * 16 + lq;
#pragma unroll
            for (int i = 0; i < 4; ++i) {
                const float gx = accg[mi][ni][i];
                const float ux = accu[mi][ni][i];
                const float inner = 0.7978845608028654f * (gx + 0.044715f * gx * gx * gx);
                const float gel = 0.5f * gx * (1.f + fast_tanh(inner));
                ((bf16*)C)[(size_t)(r0 + i) * N + cc] = (bf16)(gel * ux);
            }
        }
    }
}

// ---------------------------------------------------------------------------
// Flash attention (layouts per m89/m120 verified mappings; see round-0 notes).
// ---------------------------------------------------------------------------
__global__ __launch_bounds__(256)
void attn_k(const bf16* __restrict__ Q, const bf16* __restrict__ Kb,
            const bf16* __restrict__ Vt, bf16* __restrict__ O) {
    const int qt = blockIdx.x & 31;
    const int bh = blockIdx.x >> 5;
    const int h = bh & 7, b = bh >> 3;
    const int kvh = h >> 1;
    const int tid = threadIdx.x, lane = tid & 63, wave = tid >> 6;
    const int lq = lane & 15, quad = lane >> 4;

    __shared__ __align__(16) bf16 Ks[32 * 264];
    __shared__ __align__(16) bf16 VTs[256 * 40];
    __shared__ __align__(16) bf16 Ps[64 * 40];

    const bf16* qbase = Q + ((size_t)(b * NS + qt * 64)) * 2048 + h * 256;
    const bf16* kbase = Kb + (size_t)(b * NS) * 1024 + kvh * 256;
    const bf16* vbase = Vt + (size_t)b * 1024 * 2048 + (size_t)(kvh * 256) * 2048;

    bf16x8 aq[8];
#pragma unroll
    for (int ks = 0; ks < 8; ++ks)
        aq[ks] = *(const bf16x8*)&qbase[(size_t)(wave * 16 + lq) * 2048 + ks * 32 + quad * 8];

    f32x4 acco[16];
#pragma unroll
    for (int i = 0; i < 16; ++i) acco[i] = (f32x4){0.f, 0.f, 0.f, 0.f};
    float m_old[4] = {-1e30f, -1e30f, -1e30f, -1e30f};
    float l_old[4] = {0.f, 0.f, 0.f, 0.f};

    const int ktmax = 2 * qt + 1;
    for (int kt = 0; kt <= ktmax; ++kt) {
        __syncthreads();
#pragma unroll
        for (int j = 0; j < 4; ++j) {
            const int c = j * 256 + tid;
            const int r = c >> 5, c8 = (c & 31) * 8;
            *(uint4*)&Ks[r * 264 + c8] = *(const uint4*)&kbase[(size_t)(kt * 32 + r) * 1024 + c8];
        }
#pragma unroll
        for (int j = 0; j < 4; ++j) {
            const int c = j * 256 + tid;
            const int d = c >> 2, s8 = (c & 3) * 8;
            *(uint4*)&VTs[d * 40 + s8] = *(const uint4*)&vbase[(size_t)d * 2048 + kt * 32 + s8];
        }
        __syncthreads();

        f32x4 accs[2];
        accs[0] = (f32x4){0.f, 0.f, 0.f, 0.f};
        accs[1] = (f32x4){0.f, 0.f, 0.f, 0.f};
#pragma unroll
        for (int ks = 0; ks < 8; ++ks) {
#pragma unroll
            for (int nt = 0; nt < 2; ++nt) {
                const bf16x8 bk = *(const bf16x8*)&Ks[(nt * 16 + lq) * 264 + ks * 32 + quad * 8];
                accs[nt] = __builtin_amdgcn_mfma_f32_16x16x32_bf16(aq[ks], bk, accs[nt], 0, 0, 0);
            }
        }

        const bool diag = (kt >= 2 * qt);
        float p[2][4], rmax[4], rsum[4];
#pragma unroll
        for (int i = 0; i < 4; ++i) rmax[i] = -1e30f;
#pragma unroll
        for (int nt = 0; nt < 2; ++nt)
#pragma unroll
            for (int i = 0; i < 4; ++i) {
                float v = accs[nt][i] * SCALE_F;
                v = SOFTCAP_F * fast_tanh(v * (1.f / SOFTCAP_F));
                if (diag) {
                    const int qabs = qt * 64 + wave * 16 + quad * 4 + i;
                    const int kabs = kt * 32 + nt * 16 + lq;
                    if (kabs > qabs) v = -1e30f;
                }
                p[nt][i] = v;
                rmax[i] = fmaxf(rmax[i], v);
            }
#pragma unroll
        for (int i = 0; i < 4; ++i)
#pragma unroll
            for (int off = 8; off; off >>= 1) rmax[i] = fmaxf(rmax[i], __shfl_xor(rmax[i], off));

        float alpha[4];
#pragma unroll
        for (int i = 0; i < 4; ++i) {
            const float mn = fmaxf(m_old[i], rmax[i]);
            alpha[i] = __expf(m_old[i] - mn);
            m_old[i] = mn;
            rsum[i] = 0.f;
        }
#pragma unroll
        for (int nt = 0; nt < 2; ++nt)
#pragma unroll
            for (int i = 0; i < 4; ++i) {
                const float e = __expf(p[nt][i] - m_old[i]);
                p[nt][i] = e;
                rsum[i] += e;
            }
#pragma unroll
        for (int i = 0; i < 4; ++i) {
#pragma unroll
            for (int off = 8; off; off >>= 1) rsum[i] += __shfl_xor(rsum[i], off);
            l_old[i] = l_old[i] * alpha[i] + rsum[i];
        }
#pragma unroll
        for (int dt = 0; dt < 16; ++dt)
#pragma unroll
            for (int i = 0; i < 4; ++i) acco[dt][i] *= alpha[i];

#pragma unroll
        for (int nt = 0; nt < 2; ++nt)
#pragma unroll
            for (int i = 0; i < 4; ++i)
                Ps[(wave * 16 + quad * 4 + i) * 40 + nt * 16 + lq] = (bf16)p[nt][i];

        const bf16x8 ap = *(const bf16x8*)&Ps[(wave * 16 + lq) * 40 + quad * 8];
#pragma unroll
        for (int dt = 0; dt < 16; ++dt) {
            const bf16x8 bv = *(const bf16x8*)&VTs[(dt * 16 + lq) * 40 + quad * 8];
            acco[dt] = __builtin_amdgcn_mfma_f32_16x16x32_bf16(ap, bv, acco[dt], 0, 0, 0);
        }
    }

    bf16* obase = O + ((size_t)(b * NS + qt * 64 + wave * 16)) * 2048 + h * 256;
    float linv[4];
#pragma unroll
    for (int i = 0; i < 4; ++i) linv[i] = 1.f / l_old[i];
#pragma unroll
    for (int dt = 0; dt < 16; ++dt)
#pragma unroll
        for (int i = 0; i < 4; ++i)
            obase[(size_t)(quad * 4 + i) * 2048 + dt * 16 + lq] = (bf16)(acco[dt][i] * linv[i]);
}

// ---------------------------------------------------------------------------
// Host-side orchestration
// ---------------------------------------------------------------------------
extern "C" void kernel_launch(void* const* d_in, const int* in_sizes, int n_in,
                              void* d_out, int out_size, void* d_ws, size_t ws_size,
                              hipStream_t stream) {
    const float* x    = (const float*)d_in[0];
    // d_in[1] = mask (causal, reconstructed analytically)
    float* wq   = (float*)d_in[2];
    float* wk   = (float*)d_in[3];
    float* wv   = (float*)d_in[4];
    float* wo   = (float*)d_in[5];
    float* wg   = (float*)d_in[6];
    float* wu   = (float*)d_in[7];
    float* wd   = (float*)d_in[8];
    const float* g_in = (const float*)d_in[9];
    const float* g_pa = (const float*)d_in[10];
    const float* g_pf = (const float*)d_in[11];
    const float* g_po = (const float*)d_in[12];
    float* out = (float*)d_out;

    uint8_t* ws = (uint8_t*)d_ws;
    size_t off = 0;
    auto alloc = [&](size_t bytes) {
        void* p = ws + off;
        off += (bytes + 255) & ~(size_t)255;
        return p;
    };
    // total ws footprint: ~191 MB
    bf16* temp   = (bf16*)alloc((size_t)9216 * 1152 * 2);      // 21.2 MB transpose temp
    bf16* h_bf   = (bf16*)alloc((size_t)NROWS * 2304 * 2);     // 18.9 MB (reused as f_bf)
    uint8_t* R   = (uint8_t*)alloc((size_t)NROWS * 9216 * 2);  // 75.5 MB phased region
    float* tmp1  = (float*)alloc((size_t)NROWS * 2304 * 4);    // 37.7 MB attn_out / mlp_out
    float* h2    = (float*)alloc((size_t)NROWS * 2304 * 4);    // 37.7 MB
    (void)ws_size; (void)in_sizes; (void)n_in; (void)out_size;

    // phase-A views of R (dead before geglu writes mlp_in over them)
    bf16* q_bf   = (bf16*)R;                                     // 16.8 MB
    bf16* k_bf   = (bf16*)(R + (size_t)16777216);                //  8.4 MB
    bf16* v_t    = (bf16*)(R + (size_t)16777216 + 8388608);      //  8.4 MB
    bf16* o_bf   = (bf16*)(R + (size_t)16777216 + 2 * 8388608);  // 16.8 MB
    bf16* mlp_in = (bf16*)R;                                     // 75.5 MB (phase B)

    // ---- in-place weight conversion: f32 [K][N] -> bf16 [N][K] at same base
    // pass1: rows [0,K/2) -> temp ; pass2: rows [K/2,K) -> first half (reads
    // second half only) ; pass3: temp -> k<[0,K/2) columns. Stream-serialized.
    auto convert_weight = [&](float* W, int K, int N) {
        const int hK = K >> 1;
        const int blks = (hK >> 6) * (N >> 6);
        transpose_cvt_part<<<blks, 256, 0, stream>>>(W, N, 0, temp, hK, 0);
        transpose_cvt_part<<<blks, 256, 0, stream>>>(W, N, hK, (bf16*)W, K, hK);
        const int total = N * (hK >> 3);
        copy_expand<<<(total + 255) / 256, 256, 0, stream>>>(temp, (bf16*)W, hK, K, total);
    };
    convert_weight(wq, 2304, 2048);
    convert_weight(wk, 2304, 1024);
    convert_weight(wv, 2304, 1024);
    convert_weight(wo, 2048, 2304);
    convert_weight(wg, 2304, 9216);
    convert_weight(wu, 2304, 9216);
    convert_weight(wd, 9216, 2304);
    const bf16* wq_t = (const bf16*)wq;
    const bf16* wk_t = (const bf16*)wk;
    const bf16* wv_t = (const bf16*)wv;
    const bf16* wo_t = (const bf16*)wo;
    const bf16* wg_t = (const bf16*)wg;
    const bf16* wu_t = (const bf16*)wu;
    const bf16* wd_t = (const bf16*)wd;

    // h = rmsnorm(x, g_in) -> bf16
    rmsnorm_k<false, true><<<NROWS, 256, 0, stream>>>(x, nullptr, g_in, h_bf);

    // QKV projections
    gemm_bt<1><<<32 * 16, 256, 0, stream>>>(h_bf, wq_t, q_bf, NROWS, 2048, 2304);
    gemm_bt<1><<<32 * 8, 256, 0, stream>>>(h_bf, wk_t, k_bf, NROWS, 1024, 2304);
    gemm_bt<2><<<32 * 8, 256, 0, stream>>>(h_bf, wv_t, v_t, NROWS, 1024, 2304);  // V^T

    // RoPE in place on q,k
    rope_k<<<(NROWS * 12 * 128) / 256, 256, 0, stream>>>(q_bf, k_bf);

    // attention
    attn_k<<<NB * NHEADS * (NS / 64), 256, 0, stream>>>(q_bf, k_bf, v_t, o_bf);

    // O projection -> f32
    gemm_bt<0><<<32 * 18, 256, 0, stream>>>(o_bf, wo_t, tmp1, NROWS, 2304, 2048);

    // h2 = x + rmsnorm(attn_out, g_post_attn)
    rmsnorm_k<true, false><<<NROWS, 256, 0, stream>>>(tmp1, x, g_pa, h2);
    // f = rmsnorm(h2, g_pre_ff) -> bf16 (reuse h_bf)
    rmsnorm_k<false, true><<<NROWS, 256, 0, stream>>>(h2, nullptr, g_pf, h_bf);

    // fused GeGLU: mlp_in = gelu(f@wg) * (f@wu)   (overwrites q/k/v/o region)
    geglu_gemm<<<32 * 72, 256, 0, stream>>>(h_bf, wg_t, wu_t, mlp_in, NROWS, 9216, 2304);

    // down projection -> f32 (reuse tmp1)
    gemm_bt<0><<<32 * 18, 256, 0, stream>>>(mlp_in, wd_t, tmp1, NROWS, 2304, 9216);

    // out = h2 + rmsnorm(mlp_out, g_post_ff)
    rmsnorm_k<true, false><<<NROWS, 256, 0, stream>>>(tmp1, h2, g_po, (void*)out);
}

// Round 3
// 2029.624 us; speedup vs baseline: 1.0270x; 1.0270x over previous
//
#include <hip/hip_runtime.h>
#include <hip/hip_bf16.h>
#include <cstdint>
#include <cstddef>

typedef __bf16 bf16;
typedef __bf16 bf16x8 __attribute__((ext_vector_type(8)));
typedef __bf16 bf16x4v __attribute__((ext_vector_type(4)));
typedef float f32x4 __attribute__((ext_vector_type(4)));

#define NB 2
#define NS 2048
#define NHID 2304
#define NHEADS 8
#define NKVH 4
#define HDIM 256
#define NFF 9216
#define NROWS (NB * NS)      // 4096
#define SCALE_F 0.0625f      // 256^-0.5
#define SOFTCAP_F 50.0f

// async global->LDS DMA, 16B per lane; LDS dest = wave-uniform base + lane*16
#define ASYNC16(ldsp, gp)                                                     \
    __builtin_amdgcn_global_load_lds(                                         \
        (__attribute__((address_space(1))) void*)(gp),                        \
        (__attribute__((address_space(3))) void*)(ldsp), 16, 0, 0)

__device__ __forceinline__ float fast_tanh(float x) {
    x = fminf(fmaxf(x, -10.f), 10.f);
    float e = __expf(2.f * x);
    return (e - 1.f) / (e + 1.f);
}

// ---------------------------------------------------------------------------
// Partial transpose+convert: reads W[k][n] f32 for k in [k0, k0+64*gridK),
// writes bf16 dst[n*dstK + dstOff + (k-k0)].  64x64 tiles.
// ---------------------------------------------------------------------------
__global__ __launch_bounds__(256)
void transpose_cvt_part(const float* __restrict__ W, int N, int k0,
                        bf16* __restrict__ dst, int dstK, int dstOff) {
    __shared__ float tile[64][65];
    const int ntiles = N >> 6;
    const int tk = blockIdx.x / ntiles, tn = blockIdx.x % ntiles;
    const int kk0 = k0 + (tk << 6), n0 = tn << 6;
    const int tr = threadIdx.x >> 4, tc = threadIdx.x & 15;
#pragma unroll
    for (int j = 0; j < 4; ++j) {
        const int r = j * 16 + tr;
        const float4 v = *(const float4*)&W[(size_t)(kk0 + r) * N + n0 + tc * 4];
        tile[r][tc * 4 + 0] = v.x; tile[r][tc * 4 + 1] = v.y;
        tile[r][tc * 4 + 2] = v.z; tile[r][tc * 4 + 3] = v.w;
    }
    __syncthreads();
#pragma unroll
    for (int j = 0; j < 4; ++j) {
        const int n = j * 16 + tr;
        bf16x4v o;
        o.x = (bf16)tile[tc * 4 + 0][n];
        o.y = (bf16)tile[tc * 4 + 1][n];
        o.z = (bf16)tile[tc * 4 + 2][n];
        o.w = (bf16)tile[tc * 4 + 3][n];
        *(bf16x4v*)&dst[(size_t)(n0 + n) * dstK + dstOff + (tk << 6) + tc * 4] = o;
    }
}

// copy temp[n][0..srcK) -> dst[n*dstK + 0..srcK), 16B chunks
__global__ __launch_bounds__(256)
void copy_expand(const bf16* __restrict__ src, bf16* __restrict__ dst,
                 int srcK, int dstK, int total) {
    const int idx = blockIdx.x * 256 + threadIdx.x;
    if (idx >= total) return;
    const int cpr = srcK >> 3;
    const int n = idx / cpr, c = idx % cpr;
    *(uint4*)&dst[(size_t)n * dstK + c * 8] = *(const uint4*)&src[(size_t)n * srcK + c * 8];
}

// ---------------------------------------------------------------------------
// RMSNorm: out = [res +] rmsnorm(src, g).  One block per row, 256 thr, H=2304.
// ---------------------------------------------------------------------------
template <bool ADD, bool OBF>
__global__ __launch_bounds__(256)
void rmsnorm_k(const float* __restrict__ src, const float* __restrict__ res,
               const float* __restrict__ g, void* __restrict__ out) {
    const int row = blockIdx.x;
    const float* xr = src + (size_t)row * NHID;
    float vals[9];
    float ss = 0.f;
#pragma unroll
    for (int j = 0; j < 9; ++j) {
        vals[j] = xr[threadIdx.x + j * 256];
        ss += vals[j] * vals[j];
    }
#pragma unroll
    for (int off = 32; off > 0; off >>= 1) ss += __shfl_xor(ss, off);
    __shared__ float wss[4];
    if ((threadIdx.x & 63) == 0) wss[threadIdx.x >> 6] = ss;
    __syncthreads();
    const float scale = rsqrtf((wss[0] + wss[1] + wss[2] + wss[3]) * (1.f / NHID) + 1e-6f);
#pragma unroll
    for (int j = 0; j < 9; ++j) {
        const int c = threadIdx.x + j * 256;
        float v = vals[j] * scale * (1.f + g[c]);
        if constexpr (ADD) v += res[(size_t)row * NHID + c];
        if constexpr (OBF) ((bf16*)out)[(size_t)row * NHID + c] = (bf16)v;
        else               ((float*)out)[(size_t)row * NHID + c] = v;
    }
}

// ---------------------------------------------------------------------------
// RoPE in-place on bf16 q [4096][2048] and k [4096][1024].
// ---------------------------------------------------------------------------
__global__ __launch_bounds__(256)
void rope_k(bf16* __restrict__ q, bf16* __restrict__ k) {
    const int idx = blockIdx.x * 256 + threadIdx.x;
    const int i = idx & 127;
    const int t = idx >> 7;
    const int head = t % 12;
    const int row = t / 12;
    const int s = row & (NS - 1);
    const float ang = (float)s * exp2f(-(float)i * 0.10381025296523007f);
    float sn, cs;
    sincosf(ang, &sn, &cs);
    bf16* base = (head < 8) ? (q + (size_t)row * 2048 + head * 256 + i)
                            : (k + (size_t)row * 1024 + (head - 8) * 256 + i);
    const float x1 = (float)base[0], x2 = (float)base[128];
    base[0]   = (bf16)(x1 * cs - x2 * sn);
    base[128] = (bf16)(x2 * cs + x1 * sn);
}

// ---------------------------------------------------------------------------
// GEMM: C[M][N] = A[M][K] @ Bt[N][K]^T.  128x128 tile, 4 waves, 4x4 mfma.
// m97 structure: global_load_lds width-16 staging into UNPADDED LDS tiles
// (stride 32 bf16) — the DMA scatters base + lane*16, so layout must be
// contiguous in lane order; padding would corrupt it.
// MODE 0: C f32.  MODE 1: C bf16.  MODE 2: C bf16 transposed Vt[b][n][s].
// ---------------------------------------------------------------------------
template <int MODE>
__global__ __launch_bounds__(256)
void gemm_bt(const bf16* __restrict__ A, const bf16* __restrict__ Bt,
             void* __restrict__ C, int M, int N, int K) {
    __shared__ __align__(16) bf16 As[128 * 32];
    __shared__ __align__(16) bf16 Bs[128 * 32];
    const int tid = threadIdx.x;
    const int lane = tid & 63, wave = tid >> 6;
    const int lq = lane & 15, quad = lane >> 4;
    const int ntiles = N >> 7;
    const int tm = blockIdx.x / ntiles, tn = blockIdx.x % ntiles;
    const int m0 = tm << 7, n0 = tn << 7;
    const int wrow = (wave >> 1) << 6, wcol = (wave & 1) << 6;
    f32x4 acc[4][4];
#pragma unroll
    for (int i = 0; i < 4; ++i)
#pragma unroll
        for (int j = 0; j < 4; ++j) acc[i][j] = (f32x4){0.f, 0.f, 0.f, 0.f};

    // staging geometry: wave stages rows [wave*32, wave*32+32) of each tile,
    // 2 DMA calls/tile; lane covers (row = +lane/4, col = (lane&3)*8).
    const int wr0 = wave * 32;
    const int lrow = lane >> 2, lcol = (lane & 3) * 8;

    for (int k0 = 0; k0 < K; k0 += 32) {
        __syncthreads();
        const bf16* ga = &A[(size_t)(m0 + wr0 + lrow) * K + k0 + lcol];
        const bf16* gb = &Bt[(size_t)(n0 + wr0 + lrow) * K + k0 + lcol];
#pragma unroll
        for (int j = 0; j < 2; ++j) {
            ASYNC16(&As[(wr0 + j * 16) * 32], ga + (size_t)(j * 16) * K);
            ASYNC16(&Bs[(wr0 + j * 16) * 32], gb + (size_t)(j * 16) * K);
        }
        __syncthreads();
        bf16x8 af[4], bfr[4];
#pragma unroll
        for (int i = 0; i < 4; ++i) {
            af[i]  = *(const bf16x8*)&As[(wrow + i * 16 + lq) * 32 + quad * 8];
            bfr[i] = *(const bf16x8*)&Bs[(wcol + i * 16 + lq) * 32 + quad * 8];
        }
#pragma unroll
        for (int mi = 0; mi < 4; ++mi)
#pragma unroll
            for (int ni = 0; ni < 4; ++ni)
                acc[mi][ni] = __builtin_amdgcn_mfma_f32_16x16x32_bf16(af[mi], bfr[ni], acc[mi][ni], 0, 0, 0);
    }
#pragma unroll
    for (int mi = 0; mi < 4; ++mi) {
        const int r0 = m0 + wrow + mi * 16 + quad * 4;
#pragma unroll
        for (int ni = 0; ni < 4; ++ni) {
            const int cc = n0 + wcol + ni * 16 + lq;
#pragma unroll
            for (int i = 0; i < 4; ++i) {
                const float v = acc[mi][ni][i];
                if constexpr (MODE == 0) {
                    ((float*)C)[(size_t)(r0 + i) * N + cc] = v;
                } else if constexpr (MODE == 1) {
                    ((bf16*)C)[(size_t)(r0 + i) * N + cc] = (bf16)v;
                } else {
                    const int m = r0 + i, bb = m >> 11, ss = m & 2047;
                    ((bf16*)C)[((size_t)bb * N + cc) * 2048 + ss] = (bf16)v;
                }
            }
        }
    }
}

// ---------------------------------------------------------------------------
// Fused GeGLU GEMM: C[M][N] = gelu_tanh(A@Wg) * (A@Wu), C bf16.
// Same m97-style staging, three tiles.
// ---------------------------------------------------------------------------
__global__ __launch_bounds__(256)
void geglu_gemm(const bf16* __restrict__ A, const bf16* __restrict__ Bg,
                const bf16* __restrict__ Bu, bf16* __restrict__ C,
                int M, int N, int K) {
    __shared__ __align__(16) bf16 As[128 * 32];
    __shared__ __align__(16) bf16 Bgs[128 * 32];
    __shared__ __align__(16) bf16 Bus[128 * 32];
    const int tid = threadIdx.x;
    const int lane = tid & 63, wave = tid >> 6;
    const int lq = lane & 15, quad = lane >> 4;
    const int ntiles = N >> 7;
    const int tm = blockIdx.x / ntiles, tn = blockIdx.x % ntiles;
    const int m0 = tm << 7, n0 = tn << 7;
    const int wrow = (wave >> 1) << 6, wcol = (wave & 1) << 6;
    f32x4 accg[4][4], accu[4][4];
#pragma unroll
    for (int i = 0; i < 4; ++i)
#pragma unroll
        for (int j = 0; j < 4; ++j) {
            accg[i][j] = (f32x4){0.f, 0.f, 0.f, 0.f};
            accu[i][j] = (f32x4){0.f, 0.f, 0.f, 0.f};
        }
    const int wr0 = wave * 32;
    const int lrow = lane >> 2, lcol = (lane & 3) * 8;

    for (int k0 = 0; k0 < K; k0 += 32) {
        __syncthreads();
        const bf16* ga = &A[(size_t)(m0 + wr0 + lrow) * K + k0 + lcol];
        const bf16* gg = &Bg[(size_t)(n0 + wr0 + lrow) * K + k0 + lcol];
        const bf16* gu = &Bu[(size_t)(n0 + wr0 + lrow) * K + k0 + lcol];
#pragma unroll
        for (int j = 0; j < 2; ++j) {
            ASYNC16(&As[(wr0 + j * 16) * 32],  ga + (size_t)(j * 16) * K);
            ASYNC16(&Bgs[(wr0 + j * 16) * 32], gg + (size_t)(j * 16) * K);
            ASYNC16(&Bus[(wr0 + j * 16) * 32], gu + (size_t)(j * 16) * K);
        }
        __syncthreads();
        bf16x8 af[4], bg[4], bu[4];
#pragma unroll
        for (int i = 0; i < 4; ++i) {
            af[i] = *(const bf16x8*)&As[(wrow + i * 16 + lq) * 32 + quad * 8];
            bg[i] = *(const bf16x8*)&Bgs[(wcol + i * 16 + lq) * 32 + quad * 8];
            bu[i] = *(const bf16x8*)&Bus[(wcol + i * 16 + lq) * 32 + quad * 8];
        }
#pragma unroll
        for (int mi = 0; mi < 4; ++mi)
#pragma unroll
            for (int ni = 0; ni < 4; ++ni) {
                accg[mi][ni] = __builtin_amdgcn_mfma_f32_16x16x32_bf16(af[mi], bg[ni], accg[mi][ni], 0, 0, 0);
                accu[mi][ni] = __builtin_amdgcn_mfma_f32_16x16x32_bf16(af[mi], bu[ni], accu[mi][ni], 0, 0, 0);
            }
    }
#pragma unroll
    for (int mi = 0; mi < 4; ++mi) {
        const int r0 = m0 + wrow + mi * 16 + quad * 4;
#pragma unroll
        for (int ni = 0; ni < 4; ++ni) {
            const int cc = n0 + wcol + ni * 16 + lq;
#pragma unroll
            for (int i = 0; i < 4; ++i) {
                const float gx = accg[mi][ni][i];
                const float ux = accu[mi][ni][i];
                const float inner = 0.7978845608028654f * (gx + 0.044715f * gx * gx * gx);
                const float gel = 0.5f * gx * (1.f + fast_tanh(inner));
                ((bf16*)C)[(size_t)(r0 + i) * N + cc] = (bf16)(gel * ux);
            }
        }
    }
}

// ---------------------------------------------------------------------------
// Flash attention (unchanged from round-1 passing version).
// ---------------------------------------------------------------------------
__global__ __launch_bounds__(256)
void attn_k(const bf16* __restrict__ Q, const bf16* __restrict__ Kb,
            const bf16* __restrict__ Vt, bf16* __restrict__ O) {
    const int qt = blockIdx.x & 31;
    const int bh = blockIdx.x >> 5;
    const int h = bh & 7, b = bh >> 3;
    const int kvh = h >> 1;
    const int tid = threadIdx.x, lane = tid & 63, wave = tid >> 6;
    const int lq = lane & 15, quad = lane >> 4;

    __shared__ __align__(16) bf16 Ks[32 * 264];
    __shared__ __align__(16) bf16 VTs[256 * 40];
    __shared__ __align__(16) bf16 Ps[64 * 40];

    const bf16* qbase = Q + ((size_t)(b * NS + qt * 64)) * 2048 + h * 256;
    const bf16* kbase = Kb + (size_t)(b * NS) * 1024 + kvh * 256;
    const bf16* vbase = Vt + (size_t)b * 1024 * 2048 + (size_t)(kvh * 256) * 2048;

    bf16x8 aq[8];
#pragma unroll
    for (int ks = 0; ks < 8; ++ks)
        aq[ks] = *(const bf16x8*)&qbase[(size_t)(wave * 16 + lq) * 2048 + ks * 32 + quad * 8];

    f32x4 acco[16];
#pragma unroll
    for (int i = 0; i < 16; ++i) acco[i] = (f32x4){0.f, 0.f, 0.f, 0.f};
    float m_old[4] = {-1e30f, -1e30f, -1e30f, -1e30f};
    float l_old[4] = {0.f, 0.f, 0.f, 0.f};

    const int ktmax = 2 * qt + 1;
    for (int kt = 0; kt <= ktmax; ++kt) {
        __syncthreads();
#pragma unroll
        for (int j = 0; j < 4; ++j) {
            const int c = j * 256 + tid;
            const int r = c >> 5, c8 = (c & 31) * 8;
            *(uint4*)&Ks[r * 264 + c8] = *(const uint4*)&kbase[(size_t)(kt * 32 + r) * 1024 + c8];
        }
#pragma unroll
        for (int j = 0; j < 4; ++j) {
            const int c = j * 256 + tid;
            const int d = c >> 2, s8 = (c & 3) * 8;
            *(uint4*)&VTs[d * 40 + s8] = *(const uint4*)&vbase[(size_t)d * 2048 + kt * 32 + s8];
        }
        __syncthreads();

        f32x4 accs[2];
        accs[0] = (f32x4){0.f, 0.f, 0.f, 0.f};
        accs[1] = (f32x4){0.f, 0.f, 0.f, 0.f};
#pragma unroll
        for (int ks = 0; ks < 8; ++ks) {
#pragma unroll
            for (int nt = 0; nt < 2; ++nt) {
                const bf16x8 bk = *(const bf16x8*)&Ks[(nt * 16 + lq) * 264 + ks * 32 + quad * 8];
                accs[nt] = __builtin_amdgcn_mfma_f32_16x16x32_bf16(aq[ks], bk, accs[nt], 0, 0, 0);
            }
        }

        const bool diag = (kt >= 2 * qt);
        float p[2][4], rmax[4], rsum[4];
#pragma unroll
        for (int i = 0; i < 4; ++i) rmax[i] = -1e30f;
#pragma unroll
        for (int nt = 0; nt < 2; ++nt)
#pragma unroll
            for (int i = 0; i < 4; ++i) {
                float v = accs[nt][i] * SCALE_F;
                v = SOFTCAP_F * fast_tanh(v * (1.f / SOFTCAP_F));
                if (diag) {
                    const int qabs = qt * 64 + wave * 16 + quad * 4 + i;
                    const int kabs = kt * 32 + nt * 16 + lq;
                    if (kabs > qabs) v = -1e30f;
                }
                p[nt][i] = v;
                rmax[i] = fmaxf(rmax[i], v);
            }
#pragma unroll
        for (int i = 0; i < 4; ++i)
#pragma unroll
            for (int off = 8; off; off >>= 1) rmax[i] = fmaxf(rmax[i], __shfl_xor(rmax[i], off));

        float alpha[4];
#pragma unroll
        for (int i = 0; i < 4; ++i) {
            const float mn = fmaxf(m_old[i], rmax[i]);
            alpha[i] = __expf(m_old[i] - mn);
            m_old[i] = mn;
            rsum[i] = 0.f;
        }
#pragma unroll
        for (int nt = 0; nt < 2; ++nt)
#pragma unroll
            for (int i = 0; i < 4; ++i) {
                const float e = __expf(p[nt][i] - m_old[i]);
                p[nt][i] = e;
                rsum[i] += e;
            }
#pragma unroll
        for (int i = 0; i < 4; ++i) {
#pragma unroll
            for (int off = 8; off; off >>= 1) rsum[i] += __shfl_xor(rsum[i], off);
            l_old[i] = l_old[i] * alpha[i] + rsum[i];
        }
#pragma unroll
        for (int dt = 0; dt < 16; ++dt)
#pragma unroll
            for (int i = 0; i < 4; ++i) acco[dt][i] *= alpha[i];

#pragma unroll
        for (int nt = 0; nt < 2; ++nt)
#pragma unroll
            for (int i = 0; i < 4; ++i)
                Ps[(wave * 16 + quad * 4 + i) * 40 + nt * 16 + lq] = (bf16)p[nt][i];

        const bf16x8 ap = *(const bf16x8*)&Ps[(wave * 16 + lq) * 40 + quad * 8];
#pragma unroll
        for (int dt = 0; dt < 16; ++dt) {
            const bf16x8 bv = *(const bf16x8*)&VTs[(dt * 16 + lq) * 40 + quad * 8];
            acco[dt] = __builtin_amdgcn_mfma_f32_16x16x32_bf16(ap, bv, acco[dt], 0, 0, 0);
        }
    }

    bf16* obase = O + ((size_t)(b * NS + qt * 64 + wave * 16)) * 2048 + h * 256;
    float linv[4];
#pragma unroll
    for (int i = 0; i < 4; ++i) linv[i] = 1.f / l_old[i];
#pragma unroll
    for (int dt = 0; dt < 16; ++dt)
#pragma unroll
        for (int i = 0; i < 4; ++i)
            obase[(size_t)(quad * 4 + i) * 2048 + dt * 16 + lq] = (bf16)(acco[dt][i] * linv[i]);
}

// ---------------------------------------------------------------------------
// Host-side orchestration
// ---------------------------------------------------------------------------
extern "C" void kernel_launch(void* const* d_in, const int* in_sizes, int n_in,
                              void* d_out, int out_size, void* d_ws, size_t ws_size,
                              hipStream_t stream) {
    const float* x    = (const float*)d_in[0];
    // d_in[1] = mask (causal, reconstructed analytically)
    float* wq   = (float*)d_in[2];
    float* wk   = (float*)d_in[3];
    float* wv   = (float*)d_in[4];
    float* wo   = (float*)d_in[5];
    float* wg   = (float*)d_in[6];
    float* wu   = (float*)d_in[7];
    float* wd   = (float*)d_in[8];
    const float* g_in = (const float*)d_in[9];
    const float* g_pa = (const float*)d_in[10];
    const float* g_pf = (const float*)d_in[11];
    const float* g_po = (const float*)d_in[12];
    float* out = (float*)d_out;

    uint8_t* ws = (uint8_t*)d_ws;
    size_t off = 0;
    auto alloc = [&](size_t bytes) {
        void* p = ws + off;
        off += (bytes + 255) & ~(size_t)255;
        return p;
    };
    // total ws footprint: ~191 MB
    bf16* temp   = (bf16*)alloc((size_t)9216 * 1152 * 2);      // 21.2 MB transpose temp
    bf16* h_bf   = (bf16*)alloc((size_t)NROWS * 2304 * 2);     // 18.9 MB (reused as f_bf)
    uint8_t* R   = (uint8_t*)alloc((size_t)NROWS * 9216 * 2);  // 75.5 MB phased region
    float* tmp1  = (float*)alloc((size_t)NROWS * 2304 * 4);    // 37.7 MB attn_out / mlp_out
    float* h2    = (float*)alloc((size_t)NROWS * 2304 * 4);    // 37.7 MB
    (void)ws_size; (void)in_sizes; (void)n_in; (void)out_size;

    // phase-A views of R (dead before geglu writes mlp_in over them)
    bf16* q_bf   = (bf16*)R;                                     // 16.8 MB
    bf16* k_bf   = (bf16*)(R + (size_t)16777216);                //  8.4 MB
    bf16* v_t    = (bf16*)(R + (size_t)16777216 + 8388608);      //  8.4 MB
    bf16* o_bf   = (bf16*)(R + (size_t)16777216 + 2 * 8388608);  // 16.8 MB
    bf16* mlp_in = (bf16*)R;                                     // 75.5 MB (phase B)

    // ---- in-place weight conversion: f32 [K][N] -> bf16 [N][K] at same base
    auto convert_weight = [&](float* W, int K, int N) {
        const int hK = K >> 1;
        const int blks = (hK >> 6) * (N >> 6);
        transpose_cvt_part<<<blks, 256, 0, stream>>>(W, N, 0, temp, hK, 0);
        transpose_cvt_part<<<blks, 256, 0, stream>>>(W, N, hK, (bf16*)W, K, hK);
        const int total = N * (hK >> 3);
        copy_expand<<<(total + 255) / 256, 256, 0, stream>>>(temp, (bf16*)W, hK, K, total);
    };
    convert_weight(wq, 2304, 2048);
    convert_weight(wk, 2304, 1024);
    convert_weight(wv, 2304, 1024);
    convert_weight(wo, 2048, 2304);
    convert_weight(wg, 2304, 9216);
    convert_weight(wu, 2304, 9216);
    convert_weight(wd, 9216, 2304);
    const bf16* wq_t = (const bf16*)wq;
    const bf16* wk_t = (const bf16*)wk;
    const bf16* wv_t = (const bf16*)wv;
    const bf16* wo_t = (const bf16*)wo;
    const bf16* wg_t = (const bf16*)wg;
    const bf16* wu_t = (const bf16*)wu;
    const bf16* wd_t = (const bf16*)wd;

    // h = rmsnorm(x, g_in) -> bf16
    rmsnorm_k<false, true><<<NROWS, 256, 0, stream>>>(x, nullptr, g_in, h_bf);

    // QKV projections
    gemm_bt<1><<<32 * 16, 256, 0, stream>>>(h_bf, wq_t, q_bf, NROWS, 2048, 2304);
    gemm_bt<1><<<32 * 8, 256, 0, stream>>>(h_bf, wk_t, k_bf, NROWS, 1024, 2304);
    gemm_bt<2><<<32 * 8, 256, 0, stream>>>(h_bf, wv_t, v_t, NROWS, 1024, 2304);  // V^T

    // RoPE in place on q,k
    rope_k<<<(NROWS * 12 * 128) / 256, 256, 0, stream>>>(q_bf, k_bf);

    // attention
    attn_k<<<NB * NHEADS * (NS / 64), 256, 0, stream>>>(q_bf, k_bf, v_t, o_bf);

    // O projection -> f32
    gemm_bt<0><<<32 * 18, 256, 0, stream>>>(o_bf, wo_t, tmp1, NROWS, 2304, 2048);

    // h2 = x + rmsnorm(attn_out, g_post_attn)
    rmsnorm_k<true, false><<<NROWS, 256, 0, stream>>>(tmp1, x, g_pa, h2);
    // f = rmsnorm(h2, g_pre_ff) -> bf16 (reuse h_bf)
    rmsnorm_k<false, true><<<NROWS, 256, 0, stream>>>(h2, nullptr, g_pf, h_bf);

    // fused GeGLU: mlp_in = gelu(f@wg) * (f@wu)   (overwrites q/k/v/o region)
    geglu_gemm<<<32 * 72, 256, 0, stream>>>(h_bf, wg_t, wu_t, mlp_in, NROWS, 9216, 2304);

    // down projection -> f32 (reuse tmp1)
    gemm_bt<0><<<32 * 18, 256, 0, stream>>>(mlp_in, wd_t, tmp1, NROWS, 2304, 9216);

    // out = h2 + rmsnorm(mlp_out, g_post_ff)
    rmsnorm_k<true, false><<<NROWS, 256, 0, stream>>>(tmp1, h2, g_po, (void*)out);
}

// Round 4
// 1682.121 us; speedup vs baseline: 1.2392x; 1.2066x over previous
//
#include <hip/hip_runtime.h>
#include <hip/hip_bf16.h>
#include <cstdint>
#include <cstddef>

typedef __bf16 bf16;
typedef __bf16 bf16x8 __attribute__((ext_vector_type(8)));
typedef __bf16 bf16x4v __attribute__((ext_vector_type(4)));
typedef float f32x4 __attribute__((ext_vector_type(4)));

#define NB 2
#define NS 2048
#define NHID 2304
#define NHEADS 8
#define NKVH 4
#define HDIM 256
#define NFF 9216
#define NROWS (NB * NS)      // 4096
#define SCALE_F 0.0625f      // 256^-0.5
#define SOFTCAP_F 50.0f

// async global->LDS DMA, 16B per lane; LDS dest = wave-uniform base + lane*16
#define ASYNC16(ldsp, gp)                                                     \
    __builtin_amdgcn_global_load_lds(                                         \
        (__attribute__((address_space(1))) void*)(gp),                        \
        (__attribute__((address_space(3))) void*)(ldsp), 16, 0, 0)

__device__ __forceinline__ float fast_tanh(float x) {
    x = fminf(fmaxf(x, -10.f), 10.f);
    float e = __expf(2.f * x);
    return (e - 1.f) / (e + 1.f);
}

// ---------------------------------------------------------------------------
// Partial transpose+convert: reads W[k][n] f32 for k in [k0, k0+64*gridK),
// writes bf16 dst[n*dstK + dstOff + (k-k0)].  64x64 tiles.
// ---------------------------------------------------------------------------
__global__ __launch_bounds__(256)
void transpose_cvt_part(const float* __restrict__ W, int N, int k0,
                        bf16* __restrict__ dst, int dstK, int dstOff) {
    __shared__ float tile[64][65];
    const int ntiles = N >> 6;
    const int tk = blockIdx.x / ntiles, tn = blockIdx.x % ntiles;
    const int kk0 = k0 + (tk << 6), n0 = tn << 6;
    const int tr = threadIdx.x >> 4, tc = threadIdx.x & 15;
#pragma unroll
    for (int j = 0; j < 4; ++j) {
        const int r = j * 16 + tr;
        const float4 v = *(const float4*)&W[(size_t)(kk0 + r) * N + n0 + tc * 4];
        tile[r][tc * 4 + 0] = v.x; tile[r][tc * 4 + 1] = v.y;
        tile[r][tc * 4 + 2] = v.z; tile[r][tc * 4 + 3] = v.w;
    }
    __syncthreads();
#pragma unroll
    for (int j = 0; j < 4; ++j) {
        const int n = j * 16 + tr;
        bf16x4v o;
        o.x = (bf16)tile[tc * 4 + 0][n];
        o.y = (bf16)tile[tc * 4 + 1][n];
        o.z = (bf16)tile[tc * 4 + 2][n];
        o.w = (bf16)tile[tc * 4 + 3][n];
        *(bf16x4v*)&dst[(size_t)(n0 + n) * dstK + dstOff + (tk << 6) + tc * 4] = o;
    }
}

// copy temp[n][0..srcK) -> dst[n*dstK + 0..srcK), 16B chunks
__global__ __launch_bounds__(256)
void copy_expand(const bf16* __restrict__ src, bf16* __restrict__ dst,
                 int srcK, int dstK, int total) {
    const int idx = blockIdx.x * 256 + threadIdx.x;
    if (idx >= total) return;
    const int cpr = srcK >> 3;
    const int n = idx / cpr, c = idx % cpr;
    *(uint4*)&dst[(size_t)n * dstK + c * 8] = *(const uint4*)&src[(size_t)n * srcK + c * 8];
}

// ---------------------------------------------------------------------------
// RMSNorm: out = [res +] rmsnorm(src, g).  One block per row, 256 thr, H=2304.
// ---------------------------------------------------------------------------
template <bool ADD, bool OBF>
__global__ __launch_bounds__(256)
void rmsnorm_k(const float* __restrict__ src, const float* __restrict__ res,
               const float* __restrict__ g, void* __restrict__ out) {
    const int row = blockIdx.x;
    const float* xr = src + (size_t)row * NHID;
    float vals[9];
    float ss = 0.f;
#pragma unroll
    for (int j = 0; j < 9; ++j) {
        vals[j] = xr[threadIdx.x + j * 256];
        ss += vals[j] * vals[j];
    }
#pragma unroll
    for (int off = 32; off > 0; off >>= 1) ss += __shfl_xor(ss, off);
    __shared__ float wss[4];
    if ((threadIdx.x & 63) == 0) wss[threadIdx.x >> 6] = ss;
    __syncthreads();
    const float scale = rsqrtf((wss[0] + wss[1] + wss[2] + wss[3]) * (1.f / NHID) + 1e-6f);
#pragma unroll
    for (int j = 0; j < 9; ++j) {
        const int c = threadIdx.x + j * 256;
        float v = vals[j] * scale * (1.f + g[c]);
        if constexpr (ADD) v += res[(size_t)row * NHID + c];
        if constexpr (OBF) ((bf16*)out)[(size_t)row * NHID + c] = (bf16)v;
        else               ((float*)out)[(size_t)row * NHID + c] = v;
    }
}

// ---------------------------------------------------------------------------
// RoPE in-place on bf16 q [4096][2048] and k [4096][1024].
// ---------------------------------------------------------------------------
__global__ __launch_bounds__(256)
void rope_k(bf16* __restrict__ q, bf16* __restrict__ k) {
    const int idx = blockIdx.x * 256 + threadIdx.x;
    const int i = idx & 127;
    const int t = idx >> 7;
    const int head = t % 12;
    const int row = t / 12;
    const int s = row & (NS - 1);
    const float ang = (float)s * exp2f(-(float)i * 0.10381025296523007f);
    float sn, cs;
    sincosf(ang, &sn, &cs);
    bf16* base = (head < 8) ? (q + (size_t)row * 2048 + head * 256 + i)
                            : (k + (size_t)row * 1024 + (head - 8) * 256 + i);
    const float x1 = (float)base[0], x2 = (float)base[128];
    base[0]   = (bf16)(x1 * cs - x2 * sn);
    base[128] = (bf16)(x2 * cs + x1 * sn);
}

// ---------------------------------------------------------------------------
// GEMM: C[M][N] = A[M][K] @ Bt[N][K]^T.  128x128 tile, 4 waves, 4x4 mfma.
// m97 structure: global_load_lds width-16 staging into UNPADDED LDS tiles.
// MODE 0: C f32.  MODE 1: C bf16.  MODE 2: C bf16 transposed Vt[b][n][s].
// ---------------------------------------------------------------------------
template <int MODE>
__global__ __launch_bounds__(256)
void gemm_bt(const bf16* __restrict__ A, const bf16* __restrict__ Bt,
             void* __restrict__ C, int M, int N, int K) {
    __shared__ __align__(16) bf16 As[128 * 32];
    __shared__ __align__(16) bf16 Bs[128 * 32];
    const int tid = threadIdx.x;
    const int lane = tid & 63, wave = tid >> 6;
    const int lq = lane & 15, quad = lane >> 4;
    const int ntiles = N >> 7;
    const int tm = blockIdx.x / ntiles, tn = blockIdx.x % ntiles;
    const int m0 = tm << 7, n0 = tn << 7;
    const int wrow = (wave >> 1) << 6, wcol = (wave & 1) << 6;
    f32x4 acc[4][4];
#pragma unroll
    for (int i = 0; i < 4; ++i)
#pragma unroll
        for (int j = 0; j < 4; ++j) acc[i][j] = (f32x4){0.f, 0.f, 0.f, 0.f};

    const int wr0 = wave * 32;
    const int lrow = lane >> 2, lcol = (lane & 3) * 8;

    for (int k0 = 0; k0 < K; k0 += 32) {
        __syncthreads();
        const bf16* ga = &A[(size_t)(m0 + wr0 + lrow) * K + k0 + lcol];
        const bf16* gb = &Bt[(size_t)(n0 + wr0 + lrow) * K + k0 + lcol];
#pragma unroll
        for (int j = 0; j < 2; ++j) {
            ASYNC16(&As[(wr0 + j * 16) * 32], ga + (size_t)(j * 16) * K);
            ASYNC16(&Bs[(wr0 + j * 16) * 32], gb + (size_t)(j * 16) * K);
        }
        __syncthreads();
        bf16x8 af[4], bfr[4];
#pragma unroll
        for (int i = 0; i < 4; ++i) {
            af[i]  = *(const bf16x8*)&As[(wrow + i * 16 + lq) * 32 + quad * 8];
            bfr[i] = *(const bf16x8*)&Bs[(wcol + i * 16 + lq) * 32 + quad * 8];
        }
#pragma unroll
        for (int mi = 0; mi < 4; ++mi)
#pragma unroll
            for (int ni = 0; ni < 4; ++ni)
                acc[mi][ni] = __builtin_amdgcn_mfma_f32_16x16x32_bf16(af[mi], bfr[ni], acc[mi][ni], 0, 0, 0);
    }
#pragma unroll
    for (int mi = 0; mi < 4; ++mi) {
        const int r0 = m0 + wrow + mi * 16 + quad * 4;
#pragma unroll
        for (int ni = 0; ni < 4; ++ni) {
            const int cc = n0 + wcol + ni * 16 + lq;
#pragma unroll
            for (int i = 0; i < 4; ++i) {
                const float v = acc[mi][ni][i];
                if constexpr (MODE == 0) {
                    ((float*)C)[(size_t)(r0 + i) * N + cc] = v;
                } else if constexpr (MODE == 1) {
                    ((bf16*)C)[(size_t)(r0 + i) * N + cc] = (bf16)v;
                } else {
                    const int m = r0 + i, bb = m >> 11, ss = m & 2047;
                    ((bf16*)C)[((size_t)bb * N + cc) * 2048 + ss] = (bf16)v;
                }
            }
        }
    }
}

// ---------------------------------------------------------------------------
// Two-phase fused GeGLU GEMM: C[M][N] = gelu_tanh(A@Wg) * (A@Wu), C bf16.
// Phase 1: K-loop over (A, Wg) -> single 64-reg accumulator set -> gelu ->
// parked as bf16 (32 regs). Phase 2: same accumulators reused for (A, Wu).
// Epilogue multiplies. Register budget ~<=200/lane -> 2 waves/SIMD
// (__launch_bounds__(256,2)) vs round-3's 1 wave/SIMD at 264 regs.
// A is staged twice (19 MB, cache-resident) -- cheaper than 302 MB of gate
// scratch traffic for a 2-kernel split.
// ---------------------------------------------------------------------------
__global__ __launch_bounds__(256, 2)
void geglu_gemm(const bf16* __restrict__ A, const bf16* __restrict__ Bg,
                const bf16* __restrict__ Bu, bf16* __restrict__ C,
                int M, int N, int K) {
    __shared__ __align__(16) bf16 As[128 * 32];
    __shared__ __align__(16) bf16 Bs[128 * 32];
    const int tid = threadIdx.x;
    const int lane = tid & 63, wave = tid >> 6;
    const int lq = lane & 15, quad = lane >> 4;
    const int ntiles = N >> 7;
    const int tm = blockIdx.x / ntiles, tn = blockIdx.x % ntiles;
    const int m0 = tm << 7, n0 = tn << 7;
    const int wrow = (wave >> 1) << 6, wcol = (wave & 1) << 6;
    const int wr0 = wave * 32;
    const int lrow = lane >> 2, lcol = (lane & 3) * 8;

    f32x4 acc[4][4];
    bf16x4v gelv[4][4];

#pragma unroll
    for (int i = 0; i < 4; ++i)
#pragma unroll
        for (int j = 0; j < 4; ++j) acc[i][j] = (f32x4){0.f, 0.f, 0.f, 0.f};

    // ---- phase 1: gate = A @ Wg
    for (int k0 = 0; k0 < K; k0 += 32) {
        __syncthreads();
        const bf16* ga = &A[(size_t)(m0 + wr0 + lrow) * K + k0 + lcol];
        const bf16* gb = &Bg[(size_t)(n0 + wr0 + lrow) * K + k0 + lcol];
#pragma unroll
        for (int j = 0; j < 2; ++j) {
            ASYNC16(&As[(wr0 + j * 16) * 32], ga + (size_t)(j * 16) * K);
            ASYNC16(&Bs[(wr0 + j * 16) * 32], gb + (size_t)(j * 16) * K);
        }
        __syncthreads();
        bf16x8 af[4], bfr[4];
#pragma unroll
        for (int i = 0; i < 4; ++i) {
            af[i]  = *(const bf16x8*)&As[(wrow + i * 16 + lq) * 32 + quad * 8];
            bfr[i] = *(const bf16x8*)&Bs[(wcol + i * 16 + lq) * 32 + quad * 8];
        }
#pragma unroll
        for (int mi = 0; mi < 4; ++mi)
#pragma unroll
            for (int ni = 0; ni < 4; ++ni)
                acc[mi][ni] = __builtin_amdgcn_mfma_f32_16x16x32_bf16(af[mi], bfr[ni], acc[mi][ni], 0, 0, 0);
    }

    // gelu(gate) -> bf16 park; zero accumulators for phase 2
#pragma unroll
    for (int mi = 0; mi < 4; ++mi)
#pragma unroll
        for (int ni = 0; ni < 4; ++ni) {
#pragma unroll
            for (int i = 0; i < 4; ++i) {
                const float gx = acc[mi][ni][i];
                const float inner = 0.7978845608028654f * (gx + 0.044715f * gx * gx * gx);
                gelv[mi][ni][i] = (bf16)(0.5f * gx * (1.f + fast_tanh(inner)));
            }
            acc[mi][ni] = (f32x4){0.f, 0.f, 0.f, 0.f};
        }

    // ---- phase 2: up = A @ Wu (same accumulators, same LDS)
    for (int k0 = 0; k0 < K; k0 += 32) {
        __syncthreads();
        const bf16* ga = &A[(size_t)(m0 + wr0 + lrow) * K + k0 + lcol];
        const bf16* gb = &Bu[(size_t)(n0 + wr0 + lrow) * K + k0 + lcol];
#pragma unroll
        for (int j = 0; j < 2; ++j) {
            ASYNC16(&As[(wr0 + j * 16) * 32], ga + (size_t)(j * 16) * K);
            ASYNC16(&Bs[(wr0 + j * 16) * 32], gb + (size_t)(j * 16) * K);
        }
        __syncthreads();
        bf16x8 af[4], bfr[4];
#pragma unroll
        for (int i = 0; i < 4; ++i) {
            af[i]  = *(const bf16x8*)&As[(wrow + i * 16 + lq) * 32 + quad * 8];
            bfr[i] = *(const bf16x8*)&Bs[(wcol + i * 16 + lq) * 32 + quad * 8];
        }
#pragma unroll
        for (int mi = 0; mi < 4; ++mi)
#pragma unroll
            for (int ni = 0; ni < 4; ++ni)
                acc[mi][ni] = __builtin_amdgcn_mfma_f32_16x16x32_bf16(af[mi], bfr[ni], acc[mi][ni], 0, 0, 0);
    }

    // epilogue: C = gel * up
#pragma unroll
    for (int mi = 0; mi < 4; ++mi) {
        const int r0 = m0 + wrow + mi * 16 + quad * 4;
#pragma unroll
        for (int ni = 0; ni < 4; ++ni) {
            const int cc = n0 + wcol + ni * 16 + lq;
#pragma unroll
            for (int i = 0; i < 4; ++i)
                C[(size_t)(r0 + i) * N + cc] = (bf16)((float)gelv[mi][ni][i] * acc[mi][ni][i]);
        }
    }
}

// ---------------------------------------------------------------------------
// Flash attention (unchanged from passing version).
// ---------------------------------------------------------------------------
__global__ __launch_bounds__(256)
void attn_k(const bf16* __restrict__ Q, const bf16* __restrict__ Kb,
            const bf16* __restrict__ Vt, bf16* __restrict__ O) {
    const int qt = blockIdx.x & 31;
    const int bh = blockIdx.x >> 5;
    const int h = bh & 7, b = bh >> 3;
    const int kvh = h >> 1;
    const int tid = threadIdx.x, lane = tid & 63, wave = tid >> 6;
    const int lq = lane & 15, quad = lane >> 4;

    __shared__ __align__(16) bf16 Ks[32 * 264];
    __shared__ __align__(16) bf16 VTs[256 * 40];
    __shared__ __align__(16) bf16 Ps[64 * 40];

    const bf16* qbase = Q + ((size_t)(b * NS + qt * 64)) * 2048 + h * 256;
    const bf16* kbase = Kb + (size_t)(b * NS) * 1024 + kvh * 256;
    const bf16* vbase = Vt + (size_t)b * 1024 * 2048 + (size_t)(kvh * 256) * 2048;

    bf16x8 aq[8];
#pragma unroll
    for (int ks = 0; ks < 8; ++ks)
        aq[ks] = *(const bf16x8*)&qbase[(size_t)(wave * 16 + lq) * 2048 + ks * 32 + quad * 8];

    f32x4 acco[16];
#pragma unroll
    for (int i = 0; i < 16; ++i) acco[i] = (f32x4){0.f, 0.f, 0.f, 0.f};
    float m_old[4] = {-1e30f, -1e30f, -1e30f, -1e30f};
    float l_old[4] = {0.f, 0.f, 0.f, 0.f};

    const int ktmax = 2 * qt + 1;
    for (int kt = 0; kt <= ktmax; ++kt) {
        __syncthreads();
#pragma unroll
        for (int j = 0; j < 4; ++j) {
            const int c = j * 256 + tid;
            const int r = c >> 5, c8 = (c & 31) * 8;
            *(uint4*)&Ks[r * 264 + c8] = *(const uint4*)&kbase[(size_t)(kt * 32 + r) * 1024 + c8];
        }
#pragma unroll
        for (int j = 0; j < 4; ++j) {
            const int c = j * 256 + tid;
            const int d = c >> 2, s8 = (c & 3) * 8;
            *(uint4*)&VTs[d * 40 + s8] = *(const uint4*)&vbase[(size_t)d * 2048 + kt * 32 + s8];
        }
        __syncthreads();

        f32x4 accs[2];
        accs[0] = (f32x4){0.f, 0.f, 0.f, 0.f};
        accs[1] = (f32x4){0.f, 0.f, 0.f, 0.f};
#pragma unroll
        for (int ks = 0; ks < 8; ++ks) {
#pragma unroll
            for (int nt = 0; nt < 2; ++nt) {
                const bf16x8 bk = *(const bf16x8*)&Ks[(nt * 16 + lq) * 264 + ks * 32 + quad * 8];
                accs[nt] = __builtin_amdgcn_mfma_f32_16x16x32_bf16(aq[ks], bk, accs[nt], 0, 0, 0);
            }
        }

        const bool diag = (kt >= 2 * qt);
        float p[2][4], rmax[4], rsum[4];
#pragma unroll
        for (int i = 0; i < 4; ++i) rmax[i] = -1e30f;
#pragma unroll
        for (int nt = 0; nt < 2; ++nt)
#pragma unroll
            for (int i = 0; i < 4; ++i) {
                float v = accs[nt][i] * SCALE_F;
                v = SOFTCAP_F * fast_tanh(v * (1.f / SOFTCAP_F));
                if (diag) {
                    const int qabs = qt * 64 + wave * 16 + quad * 4 + i;
                    const int kabs = kt * 32 + nt * 16 + lq;
                    if (kabs > qabs) v = -1e30f;
                }
                p[nt][i] = v;
                rmax[i] = fmaxf(rmax[i], v);
            }
#pragma unroll
        for (int i = 0; i < 4; ++i)
#pragma unroll
            for (int off = 8; off; off >>= 1) rmax[i] = fmaxf(rmax[i], __shfl_xor(rmax[i], off));

        float alpha[4];
#pragma unroll
        for (int i = 0; i < 4; ++i) {
            const float mn = fmaxf(m_old[i], rmax[i]);
            alpha[i] = __expf(m_old[i] - mn);
            m_old[i] = mn;
            rsum[i] = 0.f;
        }
#pragma unroll
        for (int nt = 0; nt < 2; ++nt)
#pragma unroll
            for (int i = 0; i < 4; ++i) {
                const float e = __expf(p[nt][i] - m_old[i]);
                p[nt][i] = e;
                rsum[i] += e;
            }
#pragma unroll
        for (int i = 0; i < 4; ++i) {
#pragma unroll
            for (int off = 8; off; off >>= 1) rsum[i] += __shfl_xor(rsum[i], off);
            l_old[i] = l_old[i] * alpha[i] + rsum[i];
        }
#pragma unroll
        for (int dt = 0; dt < 16; ++dt)
#pragma unroll
            for (int i = 0; i < 4; ++i) acco[dt][i] *= alpha[i];

#pragma unroll
        for (int nt = 0; nt < 2; ++nt)
#pragma unroll
            for (int i = 0; i < 4; ++i)
                Ps[(wave * 16 + quad * 4 + i) * 40 + nt * 16 + lq] = (bf16)p[nt][i];

        const bf16x8 ap = *(const bf16x8*)&Ps[(wave * 16 + lq) * 40 + quad * 8];
#pragma unroll
        for (int dt = 0; dt < 16; ++dt) {
            const bf16x8 bv = *(const bf16x8*)&VTs[(dt * 16 + lq) * 40 + quad * 8];
            acco[dt] = __builtin_amdgcn_mfma_f32_16x16x32_bf16(ap, bv, acco[dt], 0, 0, 0);
        }
    }

    bf16* obase = O + ((size_t)(b * NS + qt * 64 + wave * 16)) * 2048 + h * 256;
    float linv[4];
#pragma unroll
    for (int i = 0; i < 4; ++i) linv[i] = 1.f / l_old[i];
#pragma unroll
    for (int dt = 0; dt < 16; ++dt)
#pragma unroll
        for (int i = 0; i < 4; ++i)
            obase[(size_t)(quad * 4 + i) * 2048 + dt * 16 + lq] = (bf16)(acco[dt][i] * linv[i]);
}

// ---------------------------------------------------------------------------
// Host-side orchestration
// ---------------------------------------------------------------------------
extern "C" void kernel_launch(void* const* d_in, const int* in_sizes, int n_in,
                              void* d_out, int out_size, void* d_ws, size_t ws_size,
                              hipStream_t stream) {
    const float* x    = (const float*)d_in[0];
    // d_in[1] = mask (causal, reconstructed analytically)
    float* wq   = (float*)d_in[2];
    float* wk   = (float*)d_in[3];
    float* wv   = (float*)d_in[4];
    float* wo   = (float*)d_in[5];
    float* wg   = (float*)d_in[6];
    float* wu   = (float*)d_in[7];
    float* wd   = (float*)d_in[8];
    const float* g_in = (const float*)d_in[9];
    const float* g_pa = (const float*)d_in[10];
    const float* g_pf = (const float*)d_in[11];
    const float* g_po = (const float*)d_in[12];
    float* out = (float*)d_out;

    uint8_t* ws = (uint8_t*)d_ws;
    size_t off = 0;
    auto alloc = [&](size_t bytes) {
        void* p = ws + off;
        off += (bytes + 255) & ~(size_t)255;
        return p;
    };
    // total ws footprint: ~191 MB
    bf16* temp   = (bf16*)alloc((size_t)9216 * 1152 * 2);      // 21.2 MB transpose temp
    bf16* h_bf   = (bf16*)alloc((size_t)NROWS * 2304 * 2);     // 18.9 MB (reused as f_bf)
    uint8_t* R   = (uint8_t*)alloc((size_t)NROWS * 9216 * 2);  // 75.5 MB phased region
    float* tmp1  = (float*)alloc((size_t)NROWS * 2304 * 4);    // 37.7 MB attn_out / mlp_out
    float* h2    = (float*)alloc((size_t)NROWS * 2304 * 4);    // 37.7 MB
    (void)ws_size; (void)in_sizes; (void)n_in; (void)out_size;

    // phase-A views of R (dead before geglu writes mlp_in over them)
    bf16* q_bf   = (bf16*)R;                                     // 16.8 MB
    bf16* k_bf   = (bf16*)(R + (size_t)16777216);                //  8.4 MB
    bf16* v_t    = (bf16*)(R + (size_t)16777216 + 8388608);      //  8.4 MB
    bf16* o_bf   = (bf16*)(R + (size_t)16777216 + 2 * 8388608);  // 16.8 MB
    bf16* mlp_in = (bf16*)R;                                     // 75.5 MB (phase B)

    // ---- in-place weight conversion: f32 [K][N] -> bf16 [N][K] at same base
    auto convert_weight = [&](float* W, int K, int N) {
        const int hK = K >> 1;
        const int blks = (hK >> 6) * (N >> 6);
        transpose_cvt_part<<<blks, 256, 0, stream>>>(W, N, 0, temp, hK, 0);
        transpose_cvt_part<<<blks, 256, 0, stream>>>(W, N, hK, (bf16*)W, K, hK);
        const int total = N * (hK >> 3);
        copy_expand<<<(total + 255) / 256, 256, 0, stream>>>(temp, (bf16*)W, hK, K, total);
    };
    convert_weight(wq, 2304, 2048);
    convert_weight(wk, 2304, 1024);
    convert_weight(wv, 2304, 1024);
    convert_weight(wo, 2048, 2304);
    convert_weight(wg, 2304, 9216);
    convert_weight(wu, 2304, 9216);
    convert_weight(wd, 9216, 2304);
    const bf16* wq_t = (const bf16*)wq;
    const bf16* wk_t = (const bf16*)wk;
    const bf16* wv_t = (const bf16*)wv;
    const bf16* wo_t = (const bf16*)wo;
    const bf16* wg_t = (const bf16*)wg;
    const bf16* wu_t = (const bf16*)wu;
    const bf16* wd_t = (const bf16*)wd;

    // h = rmsnorm(x, g_in) -> bf16
    rmsnorm_k<false, true><<<NROWS, 256, 0, stream>>>(x, nullptr, g_in, h_bf);

    // QKV projections
    gemm_bt<1><<<32 * 16, 256, 0, stream>>>(h_bf, wq_t, q_bf, NROWS, 2048, 2304);
    gemm_bt<1><<<32 * 8, 256, 0, stream>>>(h_bf, wk_t, k_bf, NROWS, 1024, 2304);
    gemm_bt<2><<<32 * 8, 256, 0, stream>>>(h_bf, wv_t, v_t, NROWS, 1024, 2304);  // V^T

    // RoPE in place on q,k
    rope_k<<<(NROWS * 12 * 128) / 256, 256, 0, stream>>>(q_bf, k_bf);

    // attention
    attn_k<<<NB * NHEADS * (NS / 64), 256, 0, stream>>>(q_bf, k_bf, v_t, o_bf);

    // O projection -> f32
    gemm_bt<0><<<32 * 18, 256, 0, stream>>>(o_bf, wo_t, tmp1, NROWS, 2304, 2048);

    // h2 = x + rmsnorm(attn_out, g_post_attn)
    rmsnorm_k<true, false><<<NROWS, 256, 0, stream>>>(tmp1, x, g_pa, h2);
    // f = rmsnorm(h2, g_pre_ff) -> bf16 (reuse h_bf)
    rmsnorm_k<false, true><<<NROWS, 256, 0, stream>>>(h2, nullptr, g_pf, h_bf);

    // fused GeGLU: mlp_in = gelu(f@wg) * (f@wu)   (overwrites q/k/v/o region)
    geglu_gemm<<<32 * 72, 256, 0, stream>>>(h_bf, wg_t, wu_t, mlp_in, NROWS, 9216, 2304);

    // down projection -> f32 (reuse tmp1)
    gemm_bt<0><<<32 * 18, 256, 0, stream>>>(mlp_in, wd_t, tmp1, NROWS, 2304, 9216);

    // out = h2 + rmsnorm(mlp_out, g_post_ff)
    rmsnorm_k<true, false><<<NROWS, 256, 0, stream>>>(tmp1, h2, g_po, (void*)out);
}